// Round 2
// baseline (680.111 us; speedup 1.0000x reference)
//
#include <hip/hip_runtime.h>
#include <stdint.h>

#define ATO 32000
#define SCO 1000
#define VQ_START 33100
#define VQ_END 49484
#define EMB_D 2048
#define VQ_K 256

typedef __bf16 bf16_t;
typedef bf16_t bf16x8 __attribute__((ext_vector_type(8)));
typedef float floatx4 __attribute__((ext_vector_type(4)));

// ---------------------------------------------------------------------------
// Tiny capture-safe zeroing kernel (replaces hipMemsetAsync on d_ws).
// ---------------------------------------------------------------------------
__global__ void zero_count_kernel(int* __restrict__ c) {
    if (threadIdx.x == 0) *c = 0;
}

// ---------------------------------------------------------------------------
// Kernel 1: one block per token. Non-image tokens: copy the embedding row
// (float4-vectorized, 8 KiB). Image tokens: compact (pos | img_idx<<18) into
// d_ws via a device-scope atomic counter; their output rows are written by
// kernel 2.
// ---------------------------------------------------------------------------
__global__ __launch_bounds__(256, 8) void gather_compact_kernel(
    const int* __restrict__ x,
    const float* __restrict__ token_emb,
    const float* __restrict__ added_emb,
    const float* __restrict__ numbers_emb,
    float* __restrict__ out,
    int* __restrict__ img_count,
    unsigned int* __restrict__ img_list)
{
    const int t = blockIdx.x;
    const int v = x[t];                      // uniform across block (broadcast)
    const float* src = nullptr;
    if (v >= 0 && v < ATO) {
        src = token_emb + (size_t)v * EMB_D;
    } else if (v >= ATO && v < ATO + SCO) {
        src = numbers_emb + (size_t)(v - ATO) * EMB_D;
    } else if (v >= ATO + SCO && v < VQ_START) {
        src = added_emb + (size_t)(v - ATO - SCO) * EMB_D;
    } else if (v >= VQ_START && v < VQ_END) {
        if (threadIdx.x == 0) {
            const int slot = atomicAdd(img_count, 1);
            img_list[slot] = (unsigned int)t | ((unsigned int)(v - VQ_START) << 18);
        }
        return;
    }
    float4* d4 = (float4*)(out + (size_t)t * EMB_D);
    if (src) {
        const float4* s4 = (const float4*)src;
        d4[threadIdx.x]       = s4[threadIdx.x];
        d4[threadIdx.x + 256] = s4[threadIdx.x + 256];
    } else {
        // out-of-range token id: all masks false in the reference -> zeros
        const float4 z = make_float4(0.f, 0.f, 0.f, 0.f);
        d4[threadIdx.x]       = z;
        d4[threadIdx.x + 256] = z;
    }
}

// ---------------------------------------------------------------------------
// Kernel 2: dense GEMM over compacted image tokens.
//   C[m, n] = sum_k codebook[idx_m, k] * proj_w[n, k]   (both K-major)
// Block tile: M=64 tokens, K=256 fully in registers (A split bf16 hi/lo),
// N looped in chunks of 64 staged in LDS (proj_w fp32 -> bf16 hi/lo, XOR-
// swizzled 16B groups for spread ds_read_b128 banks).
// Split-bf16 product: hi*hi + hi*lo + lo*hi ~= fp32 accuracy (~2^-17 rel).
// Wave tiling: 4 waves in 2x2 grid, each wave 32m x 32n via 16x16x32 MFMA.
// ---------------------------------------------------------------------------
__global__ __launch_bounds__(256, 1) void img_proj_kernel(
    const float* __restrict__ codebook,
    const float* __restrict__ proj_w,
    float* __restrict__ out,
    const int* __restrict__ img_count,
    const unsigned int* __restrict__ img_list)
{
    __shared__ bf16_t w_hi[64 * 32 * 8];   // 32 KiB
    __shared__ bf16_t w_lo[64 * 32 * 8];   // 32 KiB
    __shared__ unsigned int toks[64];

    const int count  = *img_count;
    const int m_base = blockIdx.x * 64;
    if (m_base >= count) return;           // uniform early-exit (inactive block)

    const int tid    = threadIdx.x;
    const int lane   = tid & 63;
    const int wave   = tid >> 6;
    const int wave_m = wave >> 1;          // 0/1 -> m half
    const int wave_n = wave & 1;           // 0/1 -> n half of the 64-chunk
    const int l15    = lane & 15;
    const int quad   = lane >> 4;

    if (tid < 64) {
        int mg = m_base + tid;
        if (mg >= count) mg = count - 1;   // clamp ragged tail (stores guarded)
        toks[tid] = img_list[mg];
    }
    __syncthreads();

    // ---- A fragments: 32 rows per wave, full K=256, split hi/lo ----
    // A layout for mfma_f32_16x16x32_bf16: lane holds A[m=lane&15][k=quad*8+j]
    bf16x8 a_hi[2][8], a_lo[2][8];
#pragma unroll
    for (int msub = 0; msub < 2; ++msub) {
        const unsigned int pk = toks[wave_m * 32 + msub * 16 + l15];
        const int row = (int)(pk >> 18);
        const float* arow = codebook + (size_t)row * VQ_K;
#pragma unroll
        for (int kk = 0; kk < 8; ++kk) {
            const float4* p = (const float4*)(arow + kk * 32 + quad * 8);
            const float4 f0 = p[0];
            const float4 f1 = p[1];
            const float f[8] = {f0.x, f0.y, f0.z, f0.w, f1.x, f1.y, f1.z, f1.w};
            bf16x8 h, l;
#pragma unroll
            for (int j = 0; j < 8; ++j) {
                const bf16_t hb = (bf16_t)f[j];
                h[j] = hb;
                l[j] = (bf16_t)(f[j] - (float)hb);
            }
            a_hi[msub][kk] = h;
            a_lo[msub][kk] = l;
        }
    }

    const floatx4 vzero = {0.f, 0.f, 0.f, 0.f};

    for (int nc = 0; nc < EMB_D; nc += 64) {
        __syncthreads();   // previous chunk's LDS reads done before restaging
        // ---- stage proj_w[nc..nc+63][0..255] -> LDS bf16 hi/lo, swizzled ----
#pragma unroll
        for (int it = 0; it < 8; ++it) {
            const int i = tid + it * 256;       // 0..2047 (64 rows x 32 groups)
            const int n = i >> 5;
            const int g = i & 31;
            const float4* p = (const float4*)(proj_w + (size_t)(nc + n) * VQ_K + g * 8);
            const float4 f0 = p[0];
            const float4 f1 = p[1];
            const float f[8] = {f0.x, f0.y, f0.z, f0.w, f1.x, f1.y, f1.z, f1.w};
            bf16x8 h, l;
#pragma unroll
            for (int j = 0; j < 8; ++j) {
                const bf16_t hb = (bf16_t)f[j];
                h[j] = hb;
                l[j] = (bf16_t)(f[j] - (float)hb);
            }
            const int off = (n * 32 + (g ^ (n & 31))) * 8;   // XOR swizzle
            *(bf16x8*)(w_hi + off) = h;
            *(bf16x8*)(w_lo + off) = l;
        }
        __syncthreads();

        floatx4 acc[2][2];
#pragma unroll
        for (int i = 0; i < 2; ++i)
#pragma unroll
            for (int j = 0; j < 2; ++j) acc[i][j] = vzero;

#pragma unroll
        for (int kk = 0; kk < 8; ++kk) {
#pragma unroll
            for (int nsub = 0; nsub < 2; ++nsub) {
                const int n_l = wave_n * 32 + nsub * 16 + l15;
                const int g   = kk * 4 + quad;
                const int off = (n_l * 32 + (g ^ (n_l & 31))) * 8;
                const bf16x8 bh = *(const bf16x8*)(w_hi + off);  // ds_read_b128
                const bf16x8 bl = *(const bf16x8*)(w_lo + off);
#pragma unroll
                for (int msub = 0; msub < 2; ++msub) {
                    acc[msub][nsub] = __builtin_amdgcn_mfma_f32_16x16x32_bf16(
                        a_lo[msub][kk], bh, acc[msub][nsub], 0, 0, 0);
                    acc[msub][nsub] = __builtin_amdgcn_mfma_f32_16x16x32_bf16(
                        a_hi[msub][kk], bl, acc[msub][nsub], 0, 0, 0);
                    acc[msub][nsub] = __builtin_amdgcn_mfma_f32_16x16x32_bf16(
                        a_hi[msub][kk], bh, acc[msub][nsub], 0, 0, 0);
                }
            }
        }

        // ---- epilogue: C/D layout col = lane&15, row = quad*4 + reg ----
#pragma unroll
        for (int msub = 0; msub < 2; ++msub) {
#pragma unroll
            for (int nsub = 0; nsub < 2; ++nsub) {
#pragma unroll
                for (int r = 0; r < 4; ++r) {
                    const int m_local = wave_m * 32 + msub * 16 + quad * 4 + r;
                    if (m_base + m_local < count) {
                        const int tok = (int)(toks[m_local] & 0x3FFFFu);
                        const int col = nc + wave_n * 32 + nsub * 16 + l15;
                        out[(size_t)tok * EMB_D + col] = acc[msub][nsub][r];
                    }
                }
            }
        }
    }
}

// ---------------------------------------------------------------------------
// Fallback (only if ws_size is too small for the compaction list): fully
// fused, workspace-free. Image tokens do a per-block VALU matvec fed from
// L2-resident proj_w. Correct but slow; exists so an undersized workspace
// can never fault the container.
// ---------------------------------------------------------------------------
__global__ __launch_bounds__(256, 4) void fused_fallback_kernel(
    const int* __restrict__ x,
    const float* __restrict__ token_emb,
    const float* __restrict__ added_emb,
    const float* __restrict__ numbers_emb,
    const float* __restrict__ codebook,
    const float* __restrict__ proj_w,
    float* __restrict__ out)
{
    const int t = blockIdx.x;
    const int v = x[t];
    float* orow = out + (size_t)t * EMB_D;

    if (v >= VQ_START && v < VQ_END) {
        __shared__ float cb[VQ_K];
        cb[threadIdx.x] = codebook[(size_t)(v - VQ_START) * VQ_K + threadIdx.x];
        __syncthreads();
#pragma unroll
        for (int j = 0; j < 8; ++j) {
            const int n = threadIdx.x + 256 * j;
            const float* wrow = proj_w + (size_t)n * VQ_K;
            float s = 0.f;
#pragma unroll 4
            for (int k = 0; k < VQ_K; k += 4) {
                const float4 w4 = *(const float4*)(wrow + k);
                s += w4.x * cb[k] + w4.y * cb[k + 1] + w4.z * cb[k + 2] + w4.w * cb[k + 3];
            }
            orow[n] = s;   // coalesced across threads
        }
        return;
    }

    const float* src = nullptr;
    if (v >= 0 && v < ATO)                  src = token_emb + (size_t)v * EMB_D;
    else if (v >= ATO && v < ATO + SCO)     src = numbers_emb + (size_t)(v - ATO) * EMB_D;
    else if (v >= ATO + SCO && v < VQ_START) src = added_emb + (size_t)(v - ATO - SCO) * EMB_D;

    float4* d4 = (float4*)orow;
    if (src) {
        const float4* s4 = (const float4*)src;
        d4[threadIdx.x]       = s4[threadIdx.x];
        d4[threadIdx.x + 256] = s4[threadIdx.x + 256];
    } else {
        const float4 z = make_float4(0.f, 0.f, 0.f, 0.f);
        d4[threadIdx.x]       = z;
        d4[threadIdx.x + 256] = z;
    }
}

// ---------------------------------------------------------------------------
extern "C" void kernel_launch(void* const* d_in, const int* in_sizes, int n_in,
                              void* d_out, int out_size, void* d_ws, size_t ws_size,
                              hipStream_t stream) {
    const int*   x           = (const int*)d_in[0];
    const float* token_emb   = (const float*)d_in[1];
    const float* added_emb   = (const float*)d_in[2];
    const float* numbers_emb = (const float*)d_in[3];
    const float* codebook    = (const float*)d_in[4];
    const float* proj_w      = (const float*)d_in[5];
    float*       out         = (float*)d_out;

    const int n_tok = in_sizes[0];   // B*S = 32768

    const size_t ws_needed = 16 + (size_t)n_tok * sizeof(unsigned int);
    if (d_ws == nullptr || ws_size < ws_needed) {
        // workspace too small: fused, workspace-free fallback
        fused_fallback_kernel<<<n_tok, 256, 0, stream>>>(
            x, token_emb, added_emb, numbers_emb, codebook, proj_w, out);
        return;
    }

    int* img_count         = (int*)d_ws;
    unsigned int* img_list = (unsigned int*)((char*)d_ws + 16);

    // d_ws is re-poisoned to 0xAA before every call: zero the atomic counter
    // with a capture-safe kernel (no runtime memset APIs inside capture).
    zero_count_kernel<<<1, 64, 0, stream>>>(img_count);

    gather_compact_kernel<<<n_tok, 256, 0, stream>>>(
        x, token_emb, added_emb, numbers_emb, out, img_count, img_list);

    const int gemm_blocks = (n_tok + 63) / 64;   // static worst-case grid
    img_proj_kernel<<<gemm_blocks, 256, 0, stream>>>(
        codebook, proj_w, out, img_count, img_list);
}